// Round 14
// baseline (126008.911 us; speedup 1.0000x reference)
//
#include <hip/hip_runtime.h>
#include <math.h>

#define HID 512
#define FEAT 128
#define SEQL 512
#define PREDL 128
#define NWG 256
#define R0 648   // producer LDS row stride: 512 h + 128 e + 8 pad
#define R1 520   // consumer/AR LDS row stride
#define RD 8     // h0 ring depth (ticks)

__device__ __forceinline__ float sigf_(float x) { return 1.0f / (1.0f + __expf(-x)); }
__device__ __forceinline__ float tanh_(float x) {
  float ax = fabsf(x);
  float e2 = __expf(-2.0f * ax);
  return copysignf((1.0f - e2) / (1.0f + e2), x);
}
__device__ __forceinline__ void stg_sc(float* p, float v) {
  __hip_atomic_store(p, v, __ATOMIC_RELAXED, __HIP_MEMORY_SCOPE_AGENT);
}

// ---- r12-verified barrier helpers (used by AR kernel only) ----------------
__device__ __forceinline__ void bar_arr(int* __restrict__ bar, int grp,
                                        int slot, int phase, int tid) {
  __syncthreads();
  if (tid == 0)
    __hip_atomic_store(bar + grp * 8 + slot, phase, __ATOMIC_RELAXED,
                       __HIP_MEMORY_SCOPE_AGENT);
  asm volatile("" ::: "memory");
}
__device__ __forceinline__ void bar_wai(int* __restrict__ bar, int grp,
                                        int phase, int tid,
                                        int* __restrict__ ldsph) {
  asm volatile("" ::: "memory");
  if (tid < 64) {
    for (;;) {
      int v = phase;
      if (tid < 8)
        v = __hip_atomic_load(bar + grp * 8 + tid, __ATOMIC_RELAXED,
                              __HIP_MEMORY_SCOPE_AGENT);
      if (__ballot(v >= phase) == 0xFFFFFFFFFFFFFFFFULL) break;
      __builtin_amdgcn_s_sleep(1);
    }
    if (tid == 0)
      __hip_atomic_store(ldsph, phase, __ATOMIC_RELAXED,
                         __HIP_MEMORY_SCOPE_WORKGROUP);
  } else {
    float z = 1.0f;
    while (__hip_atomic_load(ldsph, __ATOMIC_RELAXED,
                             __HIP_MEMORY_SCOPE_WORKGROUP) < phase) {
#pragma unroll
      for (int i = 0; i < 64; ++i) z = __builtin_fmaf(z, 1.0000001f, 1.0e-9f);
      asm volatile("" : "+v"(z));
    }
  }
  __syncthreads();
}
__device__ __forceinline__ void load1(const float4* p, float4& r) {
  asm volatile("global_load_dwordx4 %0, %1, off sc0 sc1\n\ts_waitcnt vmcnt(0)"
               : "=&v"(r) : "v"(p) : "memory");
}

// ---------------------------------------------------------------------------
// Rails kernel: 64 WGs x 1024. wg<32: LSTM0 producer (tile w = wg, batches
// 4w..4w+3, h0 state entirely in LDS — NO barriers). wg>=32: LSTM1 consumer
// of tile w = wg-32, fed via RD-deep h0 ring + monotonic counters.
// ---------------------------------------------------------------------------
__global__ __launch_bounds__(1024, 1) void k_rails(
    const float* __restrict__ x, const float* __restrict__ ENCW,
    const float* __restrict__ enc_b,
    const float* __restrict__ W0T, const float* __restrict__ W1F,
    const float* __restrict__ bih0, const float* __restrict__ bhh0,
    const float* __restrict__ bih1, const float* __restrict__ bhh1,
    float* __restrict__ h0fin,    // h0(511) -> h0B  (AR: h0b[1])
    float* __restrict__ h1fin,    // h1(510) -> h1A  (AR: h1b[0])
    float* __restrict__ ring, int* __restrict__ pctr, int* __restrict__ cctr,
    float* __restrict__ cbuf) {
  __shared__ float h0l[4 * R0];
  __shared__ float xl[4 * 132];
  __shared__ float sg[8192];
  __shared__ float h1l[4 * R1];
  __shared__ float h0in[4 * R1];

  const int wg = blockIdx.x, tid = threadIdx.x;
  const int w = wg & 31;
  const int role = wg >> 5;
  const int g = tid >> 8, u8 = (tid >> 2) & 63, b = tid & 3;
  const int n0 = g * 512 + u8 * 8;
  // combine roles: outputs ci = tid and tid+1024 -> (u=ci>>2, bb=ci&3)
  const int u1 = tid >> 2, b1 = tid & 3;
  const int u2 = (tid + 1024) >> 2, b2 = tid & 3;

  if (role == 0) {
    // =================== LSTM0 producer rail ==============================
    const float4* W0 = (const float4*)W0T;
    const float4* E4 = (const float4*)ENCW;
    float bs[8];
#pragma unroll
    for (int j = 0; j < 8; ++j) bs[j] = bih0[n0 + j] + bhh0[n0 + j];
    const int fe = (tid >> 2) & 127, be = tid & 3;
    const float encb = enc_b[fe];
    const float* hr = h0l + b * R0;
    float* slotbase = ring + (size_t)w * (RD * 2048);

    for (int i = tid; i < 4 * R0; i += 1024) h0l[i] = 0.0f;  // h0(-1)=0
    float cA = 0.0f, cB = 0.0f;
    __syncthreads();

    for (int t = 0; t < SEQL; ++t) {
      if (tid < 128) {  // stage x(t)
        const int bx = tid >> 5, f4 = tid & 31;
        *(float4*)(xl + bx * 132 + f4 * 4) =
            *(const float4*)(x + ((size_t)(w * 4 + bx) * SEQL + t) * FEAT + f4 * 4);
      }
      __syncthreads();  // s1
      if (tid < 512) {  // encoder -> e cols
        float e = encb;
#pragma unroll 8
        for (int k4 = 0; k4 < 32; ++k4) {
          const float4 wv = E4[k4 * 128 + fe];
          const float4 xv = *(const float4*)(xl + be * 132 + k4 * 4);
          e += wv.x * xv.x + wv.y * xv.y + wv.z * xv.z + wv.w * xv.w;
        }
        h0l[be * R0 + 512 + fe] = e;
      }
      __syncthreads();  // s2

      float acc[8];
#pragma unroll
      for (int j = 0; j < 8; ++j) acc[j] = bs[j];
#pragma unroll 2
      for (int k4 = 0; k4 < 160; ++k4) {
        const float4 h = *(const float4*)(hr + k4 * 4);
        const float4* wp = W0 + (size_t)k4 * 2048 + n0;
#pragma unroll
        for (int j = 0; j < 8; ++j) {
          const float4 wv = wp[j];
          acc[j] = __builtin_fmaf(wv.x, h.x,
                   __builtin_fmaf(wv.y, h.y,
                   __builtin_fmaf(wv.z, h.z,
                   __builtin_fmaf(wv.w, h.w, acc[j]))));
        }
      }
#pragma unroll
      for (int j = 0; j < 8; ++j) sg[g * 2048 + (u8 * 8 + j) * 4 + b] = acc[j];
      __syncthreads();  // s3

      if (t >= RD && tid == 0) {  // ring throttle (slack RD-1 ticks)
        while (__hip_atomic_load(cctr + w * 32, __ATOMIC_RELAXED,
                                 __HIP_MEMORY_SCOPE_AGENT) < t - (RD - 1))
          __builtin_amdgcn_s_sleep(2);
      }
      __syncthreads();  // s4

      float* slot = slotbase + (t & (RD - 1)) * 2048;
      {  // combine output ci = tid
        const int ci = tid;
        const float ig = sigf_(sg[ci]), fg = sigf_(sg[2048 + ci]);
        const float gg = tanh_(sg[4096 + ci]), og = sigf_(sg[6144 + ci]);
        const float cn = fg * cA + ig * gg;
        cA = cn;
        const float hn = og * tanh_(cn);
        h0l[b1 * R0 + u1] = hn;
        stg_sc(slot + u1 * 4 + b1, hn);
        if (t == 511) stg_sc(h0fin + w * 2048 + u1 * 4 + b1, hn);
      }
      {  // combine output ci = tid + 1024
        const int ci = tid + 1024;
        const float ig = sigf_(sg[ci]), fg = sigf_(sg[2048 + ci]);
        const float gg = tanh_(sg[4096 + ci]), og = sigf_(sg[6144 + ci]);
        const float cn = fg * cB + ig * gg;
        cB = cn;
        const float hn = og * tanh_(cn);
        h0l[b2 * R0 + u2] = hn;
        stg_sc(slot + u2 * 4 + b2, hn);
        if (t == 511) stg_sc(h0fin + w * 2048 + u2 * 4 + b2, hn);
      }
      __syncthreads();  // s5: drains stores (vmcnt) before stamp
      if (tid == 0)
        __hip_atomic_store(pctr + w * 32, t + 1, __ATOMIC_RELAXED,
                           __HIP_MEMORY_SCOPE_AGENT);
    }
    // save c0 in AR layout: cbuf[(w*8 + (u>>6))*256 + (u&63)*4 + b]
    cbuf[(size_t)(w * 8 + (u1 >> 6)) * 256 + (u1 & 63) * 4 + b1] = cA;
    cbuf[(size_t)(w * 8 + (u2 >> 6)) * 256 + (u2 & 63) * 4 + b2] = cB;
  } else {
    // =================== LSTM1 consumer rail ==============================
    const float4* W1 = (const float4*)W1F;
    float bs[8];
#pragma unroll
    for (int j = 0; j < 8; ++j) bs[j] = bih1[n0 + j] + bhh1[n0 + j];
    const int lu = tid & 511;
    const float* hr0 = h0in + b * R1;
    const float* hr1 = h1l + b * R1;
    const float* slotbase = ring + (size_t)w * (RD * 2048);

    for (int i = tid; i < 4 * R1; i += 1024) h1l[i] = 0.0f;  // h1(-1)=0
    float cA = 0.0f, cB = 0.0f;
    __syncthreads();

    for (int t = 0; t <= 510; ++t) {
      if (tid == 0) {  // wait for h0(t) (normally already posted)
        while (__hip_atomic_load(pctr + w * 32, __ATOMIC_RELAXED,
                                 __HIP_MEMORY_SCOPE_AGENT) < t + 1)
          __builtin_amdgcn_s_sleep(2);
      }
      __syncthreads();  // c0: all threads' loads issue after confirmation
      if (tid < 512) {
        const float4* sp =
            (const float4*)(slotbase + (t & (RD - 1)) * 2048) + lu;
        float4 r;
        load1(sp, r);
        h0in[0 * R1 + lu] = r.x; h0in[1 * R1 + lu] = r.y;
        h0in[2 * R1 + lu] = r.z; h0in[3 * R1 + lu] = r.w;
      }
      __syncthreads();  // c1: slot reads complete
      if (tid == 0)
        __hip_atomic_store(cctr + w * 32, t + 1, __ATOMIC_RELAXED,
                           __HIP_MEMORY_SCOPE_AGENT);

      float acc[8];
#pragma unroll
      for (int j = 0; j < 8; ++j) acc[j] = bs[j];
#pragma unroll 2
      for (int k4 = 0; k4 < 128; ++k4) {  // wih1 @ h0(t)
        const float4 h = *(const float4*)(hr0 + k4 * 4);
        const float4* wp = W1 + (size_t)k4 * 2048 + n0;
#pragma unroll
        for (int j = 0; j < 8; ++j) {
          const float4 wv = wp[j];
          acc[j] = __builtin_fmaf(wv.x, h.x,
                   __builtin_fmaf(wv.y, h.y,
                   __builtin_fmaf(wv.z, h.z,
                   __builtin_fmaf(wv.w, h.w, acc[j]))));
        }
      }
#pragma unroll 2
      for (int k4 = 0; k4 < 128; ++k4) {  // whh1 @ h1(t-1)
        const float4 h = *(const float4*)(hr1 + k4 * 4);
        const float4* wp = W1 + (size_t)(128 + k4) * 2048 + n0;
#pragma unroll
        for (int j = 0; j < 8; ++j) {
          const float4 wv = wp[j];
          acc[j] = __builtin_fmaf(wv.x, h.x,
                   __builtin_fmaf(wv.y, h.y,
                   __builtin_fmaf(wv.z, h.z,
                   __builtin_fmaf(wv.w, h.w, acc[j]))));
        }
      }
#pragma unroll
      for (int j = 0; j < 8; ++j) sg[g * 2048 + (u8 * 8 + j) * 4 + b] = acc[j];
      __syncthreads();  // c2

      {  // combine ci = tid
        const int ci = tid;
        const float ig = sigf_(sg[ci]), fg = sigf_(sg[2048 + ci]);
        const float gg = tanh_(sg[4096 + ci]), og = sigf_(sg[6144 + ci]);
        const float cn = fg * cA + ig * gg;
        cA = cn;
        const float hn = og * tanh_(cn);
        h1l[b1 * R1 + u1] = hn;
        if (t == 510) stg_sc(h1fin + w * 2048 + u1 * 4 + b1, hn);
      }
      {  // combine ci = tid + 1024
        const int ci = tid + 1024;
        const float ig = sigf_(sg[ci]), fg = sigf_(sg[2048 + ci]);
        const float gg = tanh_(sg[4096 + ci]), og = sigf_(sg[6144 + ci]);
        const float cn = fg * cB + ig * gg;
        cB = cn;
        const float hn = og * tanh_(cn);
        h1l[b2 * R1 + u2] = hn;
        if (t == 510) stg_sc(h1fin + w * 2048 + u2 * 4 + b2, hn);
      }
      __syncthreads();  // c3: protect h1l/sg/h0in against next-tick writes
    }
    cbuf[65536 + (size_t)(w * 8 + (u1 >> 6)) * 256 + (u1 & 63) * 4 + b1] = cA;
    cbuf[65536 + (size_t)(w * 8 + (u2 >> 6)) * 256 + (u2 & 63) * 4 + b2] = cB;
  }
}

// ---------------------------------------------------------------------------
// AR kernel — ROUND-12 VERBATIM (verified): LSTM1(511); 127 x {LSTM0-AR(t)
// + decode(t-1); LSTM1(t)}; final decode.
// ---------------------------------------------------------------------------
__global__ __launch_bounds__(1024, 1) void k_ar(
    const float* __restrict__ WAF, const float* __restrict__ W1F,
    const float* __restrict__ DECW, const float* __restrict__ dec_b,
    const float* __restrict__ bih0, const float* __restrict__ bhh0,
    const float* __restrict__ bih1, const float* __restrict__ bhh1,
    const float* __restrict__ bcomp,
    float* __restrict__ h0A, float* __restrict__ h0B,
    float* __restrict__ h1A, float* __restrict__ h1B,
    float* __restrict__ cbuf, int* __restrict__ bar,
    float* __restrict__ out) {
  __shared__ float hAl[4 * R1];
  __shared__ float hBl[4 * R1];
  __shared__ float sg0[1024];
  __shared__ float sg1[1024];
  __shared__ float sdec[256];
  __shared__ int lds_ph;

  const int wg = blockIdx.x, tid = threadIdx.x;
  const int grp = wg >> 3, slot = wg & 7;
  const int b = tid & 3, ul = (tid >> 2) & 63, g = tid >> 8;
  const int n = g * 512 + slot * 64 + ul;

  float* h0b[2] = {h0A, h0B};
  float* h1b[2] = {h1A, h1B};
  const float4* WA = (const float4*)WAF + n;
  const float4* W1 = (const float4*)W1F + n;
  const float4* D4 = (const float4*)DECW;

  const float baf = bih0[n] + bhh0[n] + bcomp[n];
  const float b1f = bih1[n] + bhh1[n];

  const int lu = tid & 511;
  const float* hArow = hAl + b * R1;
  const float* hBrow = hBl + b * R1;

  const int d = tid - 512;
  const int dfl = d & 15, dbb = (d >> 4) & 3, dq = (d >> 6) & 3;
  const int fdec = slot * 16 + dfl;
  const float decb = dec_b[fdec & 127];

  float c_reg = 0.0f;
  if (tid < 256) c_reg = cbuf[(size_t)wg * 256 + tid];
  else if (tid < 512) c_reg = cbuf[65536 + (size_t)wg * 256 + (tid - 256)];

  int ph = 0;
  if (tid == 0) lds_ph = 0;
  __syncthreads();

  {  // pre-phase: LSTM1(511) = f(h0(511)=h0b[1], h1(510)=h1b[0])
    const float* src = (tid < 512 ? h0b[1] : h1b[0]) + grp * 2048;
    float4 r;
    load1((const float4*)src + lu, r);
    float* dl = (tid < 512) ? hBl : hAl;
    dl[0 * R1 + lu] = r.x; dl[1 * R1 + lu] = r.y;
    dl[2 * R1 + lu] = r.z; dl[3 * R1 + lu] = r.w;
    __syncthreads();
    float a1 = b1f, a1b = 0.f;
#pragma unroll 4
    for (int k4 = 0; k4 < 128; ++k4) {
      const float4 w = W1[(size_t)k4 * 2048];
      const float4 h = *(const float4*)(hBrow + k4 * 4);
      a1 = __builtin_fmaf(w.x, h.x, a1);  a1b = __builtin_fmaf(w.y, h.y, a1b);
      a1 = __builtin_fmaf(w.z, h.z, a1);  a1b = __builtin_fmaf(w.w, h.w, a1b);
    }
#pragma unroll 4
    for (int k4 = 0; k4 < 128; ++k4) {
      const float4 w = W1[(size_t)(128 + k4) * 2048];
      const float4 h = *(const float4*)(hArow + k4 * 4);
      a1 = __builtin_fmaf(w.x, h.x, a1);  a1b = __builtin_fmaf(w.y, h.y, a1b);
      a1 = __builtin_fmaf(w.z, h.z, a1);  a1b = __builtin_fmaf(w.w, h.w, a1b);
    }
    sg1[tid] = a1 + a1b;
    __syncthreads();
    if (tid >= 256 && tid < 512) {
      const int l = tid - 256;
      const float ig = sigf_(sg1[l]), fg = sigf_(sg1[256 + l]);
      const float gg = tanh_(sg1[512 + l]), og = sigf_(sg1[768 + l]);
      const float cn = fg * c_reg + ig * gg;
      c_reg = cn;
      stg_sc(h1b[1] + grp * 2048 + slot * 256 + l, og * tanh_(cn));
    }
    bar_arr(bar, grp, slot, ++ph, tid);
    bar_wai(bar, grp, ph, tid, &lds_ph);
  }

  for (int t = SEQL; t < SEQL + PREDL - 1; ++t) {
    {  // phase 1: LSTM0-AR(t); decode h1(t-1)
      const float* src = (tid < 512 ? h1b[(t + 1) & 1] : h0b[(t + 1) & 1]) + grp * 2048;
      float4 r;
      load1((const float4*)src + lu, r);
      float* dl = (tid < 512) ? hAl : hBl;
      dl[0 * R1 + lu] = r.x; dl[1 * R1 + lu] = r.y;
      dl[2 * R1 + lu] = r.z; dl[3 * R1 + lu] = r.w;
      __syncthreads();
      float aA = baf, aAb = 0.f;
#pragma unroll 4
      for (int k4 = 0; k4 < 128; ++k4) {
        const float4 w = WA[(size_t)k4 * 2048];
        const float4 h = *(const float4*)(hArow + k4 * 4);
        aA = __builtin_fmaf(w.x, h.x, aA);  aAb = __builtin_fmaf(w.y, h.y, aAb);
        aA = __builtin_fmaf(w.z, h.z, aA);  aAb = __builtin_fmaf(w.w, h.w, aAb);
      }
#pragma unroll 4
      for (int k4 = 0; k4 < 128; ++k4) {
        const float4 w = WA[(size_t)(128 + k4) * 2048];
        const float4 h = *(const float4*)(hBrow + k4 * 4);
        aA = __builtin_fmaf(w.x, h.x, aA);  aAb = __builtin_fmaf(w.y, h.y, aAb);
        aA = __builtin_fmaf(w.z, h.z, aA);  aAb = __builtin_fmaf(w.w, h.w, aAb);
      }
      sg0[tid] = aA + aAb;
      if (tid >= 512 && tid < 768) {
        float p = 0.f;
        const float* hr = hAl + dbb * R1;
#pragma unroll 4
        for (int k4 = dq * 32; k4 < dq * 32 + 32; ++k4) {
          const float4 w = D4[k4 * 128 + fdec];
          const float4 h = *(const float4*)(hr + k4 * 4);
          p += w.x * h.x + w.y * h.y + w.z * h.z + w.w * h.w;
        }
        sdec[d] = p;
      }
      __syncthreads();
      if (tid < 256) {
        const float ig = sigf_(sg0[tid]), fg = sigf_(sg0[256 + tid]);
        const float gg = tanh_(sg0[512 + tid]), og = sigf_(sg0[768 + tid]);
        const float cn = fg * c_reg + ig * gg;
        c_reg = cn;
        stg_sc(h0b[t & 1] + grp * 2048 + slot * 256 + tid, og * tanh_(cn));
      }
      if (tid >= 512 && tid < 576) {
        const float s = decb + sdec[d] + sdec[d + 64] + sdec[d + 128] + sdec[d + 192];
        out[((size_t)(grp * 4 + dbb) * PREDL + (t - SEQL)) * FEAT + fdec] = s;
      }
      bar_arr(bar, grp, slot, ++ph, tid);
      bar_wai(bar, grp, ph, tid, &lds_ph);
    }
    {  // phase 2: LSTM1(t) over (h0(t), h1(t-1) in hAl)
      if (tid < 512) {
        const float* src = h0b[t & 1] + grp * 2048;
        float4 r;
        load1((const float4*)src + lu, r);
        hBl[0 * R1 + lu] = r.x; hBl[1 * R1 + lu] = r.y;
        hBl[2 * R1 + lu] = r.z; hBl[3 * R1 + lu] = r.w;
      }
      __syncthreads();
      float a1 = b1f, a1b = 0.f;
#pragma unroll 4
      for (int k4 = 0; k4 < 128; ++k4) {
        const float4 w = W1[(size_t)k4 * 2048];
        const float4 h = *(const float4*)(hBrow + k4 * 4);
        a1 = __builtin_fmaf(w.x, h.x, a1);  a1b = __builtin_fmaf(w.y, h.y, a1b);
        a1 = __builtin_fmaf(w.z, h.z, a1);  a1b = __builtin_fmaf(w.w, h.w, a1b);
      }
#pragma unroll 4
      for (int k4 = 0; k4 < 128; ++k4) {
        const float4 w = W1[(size_t)(128 + k4) * 2048];
        const float4 h = *(const float4*)(hArow + k4 * 4);
        a1 = __builtin_fmaf(w.x, h.x, a1);  a1b = __builtin_fmaf(w.y, h.y, a1b);
        a1 = __builtin_fmaf(w.z, h.z, a1);  a1b = __builtin_fmaf(w.w, h.w, a1b);
      }
      sg1[tid] = a1 + a1b;
      __syncthreads();
      if (tid >= 256 && tid < 512) {
        const int l = tid - 256;
        const float ig = sigf_(sg1[l]), fg = sigf_(sg1[256 + l]);
        const float gg = tanh_(sg1[512 + l]), og = sigf_(sg1[768 + l]);
        const float cn = fg * c_reg + ig * gg;
        c_reg = cn;
        stg_sc(h1b[t & 1] + grp * 2048 + slot * 256 + l, og * tanh_(cn));
      }
      bar_arr(bar, grp, slot, ++ph, tid);
      bar_wai(bar, grp, ph, tid, &lds_ph);
    }
  }

  {  // final decode: h1(638) = h1b[0], step 127
    if (tid < 512) {
      const float* src = h1b[0] + grp * 2048;
      float4 r;
      load1((const float4*)src + lu, r);
      hAl[0 * R1 + lu] = r.x; hAl[1 * R1 + lu] = r.y;
      hAl[2 * R1 + lu] = r.z; hAl[3 * R1 + lu] = r.w;
    }
    __syncthreads();
    if (tid >= 512 && tid < 768) {
      float p = 0.f;
      const float* hr = hAl + dbb * R1;
#pragma unroll 4
      for (int k4 = dq * 32; k4 < dq * 32 + 32; ++k4) {
        const float4 w = D4[k4 * 128 + fdec];
        const float4 h = *(const float4*)(hr + k4 * 4);
        p += w.x * h.x + w.y * h.y + w.z * h.z + w.w * h.w;
      }
      sdec[d] = p;
    }
    __syncthreads();
    if (tid >= 512 && tid < 576) {
      const float s = decb + sdec[d] + sdec[d + 64] + sdec[d + 128] + sdec[d + 192];
      out[((size_t)(grp * 4 + dbb) * PREDL + (PREDL - 1)) * FEAT + fdec] = s;
    }
  }
}

// ===== prologue (round-12 verbatim) ========================================
__global__ void k_b1(const float* __restrict__ enc_w,
                     const float* __restrict__ dec_w, float* __restrict__ B1) {
  const int idx = blockIdx.x * 256 + threadIdx.x;
  const int j = idx >> 9, m = idx & 511;
  float acc = 0.0f;
  for (int k = 0; k < FEAT; ++k) acc += enc_w[j * FEAT + k] * dec_w[k * HID + m];
  B1[idx] = acc;
}
__global__ void k_te(const float* __restrict__ enc_w,
                     const float* __restrict__ enc_b,
                     const float* __restrict__ dec_b, float* __restrict__ te) {
  const int j = threadIdx.x;
  float acc = enc_b[j];
  for (int k = 0; k < FEAT; ++k) acc += dec_b[k] * enc_w[j * FEAT + k];
  te[j] = acc;
}
__global__ void k_bcomp(const float* __restrict__ wih0,
                        const float* __restrict__ te, float* __restrict__ bc) {
  const int nn = blockIdx.x * 256 + threadIdx.x;
  float acc = 0.0f;
  for (int j = 0; j < FEAT; ++j) acc += wih0[nn * FEAT + j] * te[j];
  bc[nn] = acc;
}
__global__ void k_w0t(const float* __restrict__ whh0,
                      const float* __restrict__ wih0, float* __restrict__ W) {
  const int idx = blockIdx.x * 256 + threadIdx.x;
  const int k4 = idx >> 11, rr = idx & 2047;
  const int k = k4 * 4;
  float4 v;
  if (k < 512) {
    const float* p = whh0 + (size_t)rr * 512 + k;
    v = make_float4(p[0], p[1], p[2], p[3]);
  } else {
    const float* p = wih0 + (size_t)rr * 128 + (k - 512);
    v = make_float4(p[0], p[1], p[2], p[3]);
  }
  ((float4*)W)[idx] = v;
}
__global__ void k_w1f(const float* __restrict__ wih1,
                      const float* __restrict__ whh1, float* __restrict__ W) {
  const int idx = blockIdx.x * 256 + threadIdx.x;
  const int k4 = idx >> 11, rr = idx & 2047;
  const int k = k4 * 4;
  const float* p = (k < 512) ? (wih1 + (size_t)rr * 512 + k)
                             : (whh1 + (size_t)rr * 512 + (k - 512));
  ((float4*)W)[idx] = make_float4(p[0], p[1], p[2], p[3]);
}
__global__ void k_waf(const float* __restrict__ wih0,
                      const float* __restrict__ B1,
                      const float* __restrict__ whh0, float* __restrict__ W) {
  const int idx = blockIdx.x * 256 + threadIdx.x;
  const int k4 = idx >> 11, rr = idx & 2047;
  const int k = k4 * 4;
  float4 v;
  if (k < 512) {
    float s0 = 0, s1 = 0, s2 = 0, s3 = 0;
    const float* wr = wih0 + (size_t)rr * 128;
    for (int j = 0; j < 128; ++j) {
      const float wv = wr[j];
      const float* bp = B1 + (size_t)j * 512 + k;
      s0 += wv * bp[0]; s1 += wv * bp[1]; s2 += wv * bp[2]; s3 += wv * bp[3];
    }
    v = make_float4(s0, s1, s2, s3);
  } else {
    const float* p = whh0 + (size_t)rr * 512 + (k - 512);
    v = make_float4(p[0], p[1], p[2], p[3]);
  }
  ((float4*)W)[idx] = v;
}
__global__ void k_encw(const float* __restrict__ enc_w, float* __restrict__ W) {
  const int idx = blockIdx.x * 256 + threadIdx.x;
  const int k4 = idx >> 7, f = idx & 127;
  const float* p = enc_w + (size_t)f * 128 + k4 * 4;
  ((float4*)W)[idx] = make_float4(p[0], p[1], p[2], p[3]);
}
__global__ void k_decw(const float* __restrict__ dec_w, float* __restrict__ W) {
  const int idx = blockIdx.x * 256 + threadIdx.x;
  const int k4 = idx >> 7, f = idx & 127;
  const float* p = dec_w + (size_t)f * 512 + k4 * 4;
  ((float4*)W)[idx] = make_float4(p[0], p[1], p[2], p[3]);
}

// ===== ws layout (floats) ==================================================
#define WS_H0A 0
#define WS_H0B 65536
#define WS_H1A 131072
#define WS_H1B 196608
#define WS_CBUF 262144
#define WS_BART 393216
#define WS_BARA 397312
#define WS_TE 401408
#define WS_BCOMP 401536
#define WS_B1 403584
#define WS_ENCW 469120
#define WS_DECW 485504
#define WS_W0T 551040
#define WS_W1F 1861760
#define WS_WAF 3958912
#define WS_RING 6056064
#define WS_PCTR 6580352
#define WS_CCTR 6581376
// end 6582400 floats = 26.3 MB

extern "C" void kernel_launch(void* const* d_in, const int* in_sizes, int n_in,
                              void* d_out, int out_size, void* d_ws,
                              size_t ws_size, hipStream_t stream) {
  const float* x     = (const float*)d_in[0];
  const float* enc_w = (const float*)d_in[1];
  const float* enc_b = (const float*)d_in[2];
  const float* dec_w = (const float*)d_in[3];
  const float* dec_b = (const float*)d_in[4];
  const float* wih0  = (const float*)d_in[5];
  const float* whh0  = (const float*)d_in[6];
  const float* bih0  = (const float*)d_in[7];
  const float* bhh0  = (const float*)d_in[8];
  const float* wih1  = (const float*)d_in[9];
  const float* whh1  = (const float*)d_in[10];
  const float* bih1  = (const float*)d_in[11];
  const float* bhh1  = (const float*)d_in[12];
  float* out = (float*)d_out;

  float* ws = (float*)d_ws;
  float* h0A = ws + WS_H0A;
  float* h0B = ws + WS_H0B;
  float* h1A = ws + WS_H1A;
  float* h1B = ws + WS_H1B;
  float* cbuf = ws + WS_CBUF;
  int* barT = (int*)(ws + WS_BART);
  int* barA = (int*)(ws + WS_BARA);
  float* te = ws + WS_TE;
  float* bcomp = ws + WS_BCOMP;
  float* B1 = ws + WS_B1;
  float* ENCW = ws + WS_ENCW;
  float* DECW = ws + WS_DECW;
  float* W0T = ws + WS_W0T;
  float* W1F = ws + WS_W1F;
  float* WAF = ws + WS_WAF;
  float* ring = ws + WS_RING;
  int* pctr = (int*)(ws + WS_PCTR);
  int* cctr = (int*)(ws + WS_CCTR);
  (void)barT;

  // zero h states + barrier flags + rail counters each launch
  (void)hipMemsetAsync(ws, 0, (size_t)262144 * sizeof(float), stream);
  (void)hipMemsetAsync(ws + WS_BART, 0, (size_t)8192 * sizeof(float), stream);
  (void)hipMemsetAsync(ws + WS_PCTR, 0, (size_t)2048 * sizeof(int), stream);

  k_b1<<<256, 256, 0, stream>>>(enc_w, dec_w, B1);
  k_te<<<1, 128, 0, stream>>>(enc_w, enc_b, dec_b, te);
  k_bcomp<<<8, 256, 0, stream>>>(wih0, te, bcomp);
  k_w0t<<<1280, 256, 0, stream>>>(whh0, wih0, W0T);
  k_w1f<<<2048, 256, 0, stream>>>(wih1, whh1, W1F);
  k_waf<<<2048, 256, 0, stream>>>(wih0, B1, whh0, WAF);
  k_encw<<<16, 256, 0, stream>>>(enc_w, ENCW);
  k_decw<<<64, 256, 0, stream>>>(dec_w, DECW);

  // teacher phase: barrier-free producer/consumer rails (64 WGs)
  k_rails<<<64, 1024, 0, stream>>>(
      x, ENCW, enc_b, W0T, W1F, bih0, bhh0, bih1, bhh1,
      h0B, h1A, ring, pctr, cctr, cbuf);

  // autoregressive phase (round-12 verified)
  k_ar<<<NWG, 1024, 0, stream>>>(
      WAF, W1F, DECW, dec_b, bih0, bhh0, bih1, bhh1, bcomp,
      h0A, h0B, h1A, h1B, cbuf, barA, out);
}